// Round 4
// baseline (291.365 us; speedup 1.0000x reference)
//
#include <hip/hip_runtime.h>

#define HID 20

// Scalar SiLU via native exp2/rcp. Same per-lane formula/op-order as all
// prior rounds -> bit-identical results (absmax 0.0).
__device__ __forceinline__ float si(float a) {
    float e = __builtin_amdgcn_exp2f(-1.442695040888963f * a);
    return a * __builtin_amdgcn_rcpf(1.0f + e);
}

// R4 knowledge: v_pk_fma_f32 is half-rate on gfx950 (FP32 pipe = 1 FMA/lane/cy
// either way; 157.3 TF spec has no dual-issue). So: plain scalar FMAs, and the
// only levers are issue-port idle time and trans overlap. This round: 3 points
// per thread, JB=4 -> 12 independent acc chains; 3x busy work per SGPR
// weight-block load amortizes the exposed s_load latency that capped R1 at
// 72% VALUBusy. Weights stay global-pointer (uniform -> s_load bursts, K$-hit).
__device__ __forceinline__ void layer20_3(const float* __restrict__ W,
                                          const float* __restrict__ b,
                                          const float* __restrict__ h0,
                                          const float* __restrict__ h1,
                                          const float* __restrict__ h2,
                                          float* __restrict__ o0,
                                          float* __restrict__ o1,
                                          float* __restrict__ o2) {
    #pragma unroll
    for (int jb = 0; jb < HID; jb += 4) {
        float b0v = b[jb], b1v = b[jb + 1], b2v = b[jb + 2], b3v = b[jb + 3];
        float a00 = b0v, a01 = b1v, a02 = b2v, a03 = b3v;   // point 0
        float a10 = b0v, a11 = b1v, a12 = b2v, a13 = b3v;   // point 1
        float a20 = b0v, a21 = b1v, a22 = b2v, a23 = b3v;   // point 2
        #pragma unroll
        for (int i = 0; i < HID; ++i) {
            float w0 = W[(jb + 0) * HID + i];
            float w1 = W[(jb + 1) * HID + i];
            float w2 = W[(jb + 2) * HID + i];
            float w3 = W[(jb + 3) * HID + i];
            float x0 = h0[i], x1 = h1[i], x2 = h2[i];
            a00 = __builtin_fmaf(x0, w0, a00);
            a10 = __builtin_fmaf(x1, w0, a10);
            a20 = __builtin_fmaf(x2, w0, a20);
            a01 = __builtin_fmaf(x0, w1, a01);
            a11 = __builtin_fmaf(x1, w1, a11);
            a21 = __builtin_fmaf(x2, w1, a21);
            a02 = __builtin_fmaf(x0, w2, a02);
            a12 = __builtin_fmaf(x1, w2, a12);
            a22 = __builtin_fmaf(x2, w2, a22);
            a03 = __builtin_fmaf(x0, w3, a03);
            a13 = __builtin_fmaf(x1, w3, a13);
            a23 = __builtin_fmaf(x2, w3, a23);
        }
        o0[jb] = si(a00); o0[jb + 1] = si(a01); o0[jb + 2] = si(a02); o0[jb + 3] = si(a03);
        o1[jb] = si(a10); o1[jb + 1] = si(a11); o1[jb + 2] = si(a12); o1[jb + 3] = si(a13);
        o2[jb] = si(a20); o2[jb + 1] = si(a21); o2[jb + 2] = si(a22); o2[jb + 3] = si(a23);
    }
}

// Live set: 3x20 h (60) + 3x20 ping-pong partial (<=48 live at peak) + 12 acc
// + temps ~ 140-155 VGPR. (256,3): cap ~168, 3 waves/SIMD; 12 in-wave chains
// carry the latency hiding instead of TLP.
__global__ __launch_bounds__(256, 3) void SpringEquationNN_70102456205450_kernel(
    const float* __restrict__ t,
    const float* __restrict__ W0, const float* __restrict__ b0,
    const float* __restrict__ W1, const float* __restrict__ b1,
    const float* __restrict__ W2, const float* __restrict__ b2,
    const float* __restrict__ W3, const float* __restrict__ b3,
    const float* __restrict__ W4, const float* __restrict__ b4,
    const float* __restrict__ W5, const float* __restrict__ b5,
    const float* __restrict__ W6, const float* __restrict__ b6,
    const float* __restrict__ W7, const float* __restrict__ b7,
    float* __restrict__ out, int n)
{
    int idx = blockIdx.x * blockDim.x + threadIdx.x;
    int p0 = 3 * idx;
    if (p0 >= n) return;

    // 12B/lane contiguous -> coalesced. Clamp tail reads (compute garbage,
    // store guarded below); only the single last thread is affected.
    int i1 = p0 + 1 < n ? p0 + 1 : n - 1;
    int i2 = p0 + 2 < n ? p0 + 2 : n - 1;
    float x0 = t[p0], x1 = t[i1], x2 = t[i2];

    float h0[HID], h1[HID], h2[HID];
    float g0[HID], g1[HID], g2[HID];

    // Layer 0: 1 -> 20 on all three points.
    #pragma unroll
    for (int j = 0; j < HID; ++j) {
        float w = W0[j], bb = b0[j];
        h0[j] = si(__builtin_fmaf(x0, w, bb));
        h1[j] = si(__builtin_fmaf(x1, w, bb));
        h2[j] = si(__builtin_fmaf(x2, w, bb));
    }

    // Layers 1..6: 20 -> 20, SiLU (ping-pong, ends back in h).
    layer20_3(W1, b1, h0, h1, h2, g0, g1, g2);
    layer20_3(W2, b2, g0, g1, g2, h0, h1, h2);
    layer20_3(W3, b3, h0, h1, h2, g0, g1, g2);
    layer20_3(W4, b4, g0, g1, g2, h0, h1, h2);
    layer20_3(W5, b5, h0, h1, h2, g0, g1, g2);
    layer20_3(W6, b6, g0, g1, g2, h0, h1, h2);

    // Layer 7: 20 -> 1, serial ascending-i chain per point (bit-exact order).
    float b7v = b7[0];
    float accA = b7v, accB = b7v, accC = b7v;
    #pragma unroll
    for (int i = 0; i < HID; ++i) {
        float w = W7[i];
        accA = __builtin_fmaf(h0[i], w, accA);
        accB = __builtin_fmaf(h1[i], w, accB);
        accC = __builtin_fmaf(h2[i], w, accC);
    }

    out[p0] = accA;
    if (p0 + 1 < n) out[p0 + 1] = accB;
    if (p0 + 2 < n) out[p0 + 2] = accC;
}

extern "C" void kernel_launch(void* const* d_in, const int* in_sizes, int n_in,
                              void* d_out, int out_size, void* d_ws, size_t ws_size,
                              hipStream_t stream) {
    const float* t  = (const float*)d_in[0];
    const float* W0 = (const float*)d_in[1];
    const float* b0 = (const float*)d_in[2];
    const float* W1 = (const float*)d_in[3];
    const float* b1 = (const float*)d_in[4];
    const float* W2 = (const float*)d_in[5];
    const float* b2 = (const float*)d_in[6];
    const float* W3 = (const float*)d_in[7];
    const float* b3 = (const float*)d_in[8];
    const float* W4 = (const float*)d_in[9];
    const float* b4 = (const float*)d_in[10];
    const float* W5 = (const float*)d_in[11];
    const float* b5 = (const float*)d_in[12];
    const float* W6 = (const float*)d_in[13];
    const float* b6 = (const float*)d_in[14];
    const float* W7 = (const float*)d_in[15];
    const float* b7 = (const float*)d_in[16];
    float* out = (float*)d_out;

    int n = in_sizes[0];                     // N points
    int points_per_thread = 3;
    int threads = (n + points_per_thread - 1) / points_per_thread;
    int block = 256;
    int grid = (threads + block - 1) / block;
    SpringEquationNN_70102456205450_kernel<<<grid, block, 0, stream>>>(
        t, W0, b0, W1, b1, W2, b2, W3, b3, W4, b4, W5, b5, W6, b6, W7, b7,
        out, n);
}

// Round 5
// 284.439 us; speedup vs baseline: 1.0243x; 1.0243x over previous
//
#include <hip/hip_runtime.h>

#define HID 20

typedef float v2f __attribute__((ext_vector_type(2)));

// Native-instruction SiLU on a packed pair. exp/rcp are scalar trans ops
// (quarter-rate); surrounding muls pack. Formula bit-identical to all rounds.
__device__ __forceinline__ v2f silu2(v2f a) {
    v2f s = a * (-1.442695040888963f);
    float e0 = __builtin_amdgcn_exp2f(s.x);
    float e1 = __builtin_amdgcn_exp2f(s.y);
    v2f rc;
    rc.x = __builtin_amdgcn_rcpf(1.0f + e0);
    rc.y = __builtin_amdgcn_rcpf(1.0f + e1);
    return a * rc;
}

// 20->20 layer on a pair of points, j-blocked by JB with i as the middle
// loop (R1: 4 independent acc chains -> dep distance covers fma latency;
// best measured structure, 83us rocprof). Weights via wave-uniform global
// pointers -> SGPR s_load bursts, K$-resident.
template <int JB>
__device__ __forceinline__ void layer20(const float* __restrict__ W,
                                        const float* __restrict__ b,
                                        const v2f* __restrict__ h,
                                        v2f* __restrict__ hn) {
    static_assert(HID % JB == 0, "JB must divide HID");
    #pragma unroll
    for (int jb = 0; jb < HID; jb += JB) {
        v2f acc[JB];
        #pragma unroll
        for (int j = 0; j < JB; ++j) {
            float bj = b[jb + j];
            acc[j] = (v2f){bj, bj};
        }
        #pragma unroll
        for (int i = 0; i < HID; ++i) {
            v2f hi = h[i];
            #pragma unroll
            for (int j = 0; j < JB; ++j) {
                float w = W[(jb + j) * HID + i];
                acc[j] = __builtin_elementwise_fma(hi, (v2f){w, w}, acc[j]);
            }
        }
        #pragma unroll
        for (int j = 0; j < JB; ++j)
            hn[jb + j] = silu2(acc[j]);
    }
}

// R5 change vs R1: __launch_bounds__(256, 8) instead of (256, 4).
// Evidence: OccupancyPercent tracks the 2nd arg as a waves/EU CAP on this
// toolchain (R4's (256,3) measured 36.6-37.7% ~= 3/8 exactly; R0/R1 (256,4)
// stuck at ~40%). R1's VGPR=44 fits the 64-VGPR budget of 8 waves/EU, so
// raising the floor/cap to 8 doubles residency; extra waves cover the
// s_load bursts and quarter-rate exp2/rcp stretches that are the 28% idle.
__global__ __launch_bounds__(256, 8) void SpringEquationNN_70102456205450_kernel(
    const float* __restrict__ t,
    const float* __restrict__ W0, const float* __restrict__ b0,
    const float* __restrict__ W1, const float* __restrict__ b1,
    const float* __restrict__ W2, const float* __restrict__ b2,
    const float* __restrict__ W3, const float* __restrict__ b3,
    const float* __restrict__ W4, const float* __restrict__ b4,
    const float* __restrict__ W5, const float* __restrict__ b5,
    const float* __restrict__ W6, const float* __restrict__ b6,
    const float* __restrict__ W7, const float* __restrict__ b7,
    float* __restrict__ out, int n)
{
    int idx = blockIdx.x * blockDim.x + threadIdx.x;   // pair index
    int p0 = 2 * idx;
    if (p0 >= n) return;

    // Coalesced 8B load of two consecutive points (N is even: 1048576).
    v2f x = *(const v2f*)(t + p0);

    v2f h[HID], hn[HID];

    // Layer 0: 1 -> 20 on both points
    #pragma unroll
    for (int j = 0; j < HID; ++j) {
        float w = W0[j], bb = b0[j];
        v2f a = __builtin_elementwise_fma(x, (v2f){w, w}, (v2f){bb, bb});
        h[j] = silu2(a);
    }

    // Layers 1..6: 20 -> 20, SiLU
    layer20<4>(W1, b1, h, hn);
    layer20<4>(W2, b2, hn, h);
    layer20<4>(W3, b3, h, hn);
    layer20<4>(W4, b4, hn, h);
    layer20<4>(W5, b5, h, hn);
    layer20<4>(W6, b6, hn, h);

    // Layer 7: 20 -> 1 (no activation). Serial ascending-i chain preserves
    // the exact reference summation order.
    float b7v = b7[0];
    v2f acc = {b7v, b7v};
    #pragma unroll
    for (int i = 0; i < HID; ++i) {
        float w = W7[i];
        acc = __builtin_elementwise_fma(h[i], (v2f){w, w}, acc);
    }

    // Coalesced 8B store.
    *(v2f*)(out + p0) = acc;
}

extern "C" void kernel_launch(void* const* d_in, const int* in_sizes, int n_in,
                              void* d_out, int out_size, void* d_ws, size_t ws_size,
                              hipStream_t stream) {
    const float* t  = (const float*)d_in[0];
    const float* W0 = (const float*)d_in[1];
    const float* b0 = (const float*)d_in[2];
    const float* W1 = (const float*)d_in[3];
    const float* b1 = (const float*)d_in[4];
    const float* W2 = (const float*)d_in[5];
    const float* b2 = (const float*)d_in[6];
    const float* W3 = (const float*)d_in[7];
    const float* b3 = (const float*)d_in[8];
    const float* W4 = (const float*)d_in[9];
    const float* b4 = (const float*)d_in[10];
    const float* W5 = (const float*)d_in[11];
    const float* b5 = (const float*)d_in[12];
    const float* W6 = (const float*)d_in[13];
    const float* b6 = (const float*)d_in[14];
    const float* W7 = (const float*)d_in[15];
    const float* b7 = (const float*)d_in[16];
    float* out = (float*)d_out;

    int n = in_sizes[0];             // N points
    int pairs = (n + 1) / 2;         // threads (N=1048576 -> 524288)
    int block = 256;
    int grid = (pairs + block - 1) / block;
    SpringEquationNN_70102456205450_kernel<<<grid, block, 0, stream>>>(
        t, W0, b0, W1, b1, W2, b2, W3, b3, W4, b4, W5, b5, W6, b6, W7, b7,
        out, n);
}

// Round 6
// 154.714 us; speedup vs baseline: 1.8832x; 1.8385x over previous
//
#include <hip/hip_runtime.h>

#define HID 20

typedef float v2f __attribute__((ext_vector_type(2)));

// Native-instruction SiLU on a packed pair. exp/rcp are scalar trans ops
// (quarter-rate); surrounding muls pack. Formula bit-identical to all rounds.
__device__ __forceinline__ v2f silu2(v2f a) {
    v2f s = a * (-1.442695040888963f);
    float e0 = __builtin_amdgcn_exp2f(s.x);
    float e1 = __builtin_amdgcn_exp2f(s.y);
    v2f rc;
    rc.x = __builtin_amdgcn_rcpf(1.0f + e0);
    rc.y = __builtin_amdgcn_rcpf(1.0f + e1);
    return a * rc;
}

// 20->20 layer on a pair of points, j-blocked by JB with i as the middle
// loop (R1: 4 independent acc chains -> dep distance covers fma latency;
// best measured structure, 83us rocprof). Weights via wave-uniform global
// pointers -> SGPR s_load bursts, K$-resident.
template <int JB>
__device__ __forceinline__ void layer20(const float* __restrict__ W,
                                        const float* __restrict__ b,
                                        const v2f* __restrict__ h,
                                        v2f* __restrict__ hn) {
    static_assert(HID % JB == 0, "JB must divide HID");
    #pragma unroll
    for (int jb = 0; jb < HID; jb += JB) {
        v2f acc[JB];
        #pragma unroll
        for (int j = 0; j < JB; ++j) {
            float bj = b[jb + j];
            acc[j] = (v2f){bj, bj};
        }
        #pragma unroll
        for (int i = 0; i < HID; ++i) {
            v2f hi = h[i];
            #pragma unroll
            for (int j = 0; j < JB; ++j) {
                float w = W[(jb + j) * HID + i];
                acc[j] = __builtin_elementwise_fma(hi, (v2f){w, w}, acc[j]);
            }
        }
        #pragma unroll
        for (int j = 0; j < JB; ++j)
            hn[jb + j] = silu2(acc[j]);
    }
}

// R6 change vs R1 (83us best): decouple regalloc budget from residency cap.
// Evidence chain: launch_bounds 2nd arg tracks measured occupancy as a CEILING
// (R4 min=3 -> 36.6%~3/8; R0/R1 min=4 -> ~40%; R5 min=8 -> 61%) AND as the
// regalloc target (R5: min=8 crushed VGPR to 32 + 284MB scratch). So:
// amdgpu_waves_per_eu(4, 8): min=4 reproduces R1's proven 44-VGPR no-spill
// schedule; max=8 lets HW fill to 8 waves/SIMD to cover s_load bursts and
// quarter-rate trans stretches (the 28% idle).
__global__ __launch_bounds__(256)
__attribute__((amdgpu_waves_per_eu(4, 8)))
void SpringEquationNN_70102456205450_kernel(
    const float* __restrict__ t,
    const float* __restrict__ W0, const float* __restrict__ b0,
    const float* __restrict__ W1, const float* __restrict__ b1,
    const float* __restrict__ W2, const float* __restrict__ b2,
    const float* __restrict__ W3, const float* __restrict__ b3,
    const float* __restrict__ W4, const float* __restrict__ b4,
    const float* __restrict__ W5, const float* __restrict__ b5,
    const float* __restrict__ W6, const float* __restrict__ b6,
    const float* __restrict__ W7, const float* __restrict__ b7,
    float* __restrict__ out, int n)
{
    int idx = blockIdx.x * blockDim.x + threadIdx.x;   // pair index
    int p0 = 2 * idx;
    if (p0 >= n) return;

    // Coalesced 8B load of two consecutive points (N is even: 1048576).
    v2f x = *(const v2f*)(t + p0);

    v2f h[HID], hn[HID];

    // Layer 0: 1 -> 20 on both points
    #pragma unroll
    for (int j = 0; j < HID; ++j) {
        float w = W0[j], bb = b0[j];
        v2f a = __builtin_elementwise_fma(x, (v2f){w, w}, (v2f){bb, bb});
        h[j] = silu2(a);
    }

    // Layers 1..6: 20 -> 20, SiLU
    layer20<4>(W1, b1, h, hn);
    layer20<4>(W2, b2, hn, h);
    layer20<4>(W3, b3, h, hn);
    layer20<4>(W4, b4, hn, h);
    layer20<4>(W5, b5, h, hn);
    layer20<4>(W6, b6, hn, h);

    // Layer 7: 20 -> 1 (no activation). Serial ascending-i chain preserves
    // the exact reference summation order.
    float b7v = b7[0];
    v2f acc = {b7v, b7v};
    #pragma unroll
    for (int i = 0; i < HID; ++i) {
        float w = W7[i];
        acc = __builtin_elementwise_fma(h[i], (v2f){w, w}, acc);
    }

    // Coalesced 8B store.
    *(v2f*)(out + p0) = acc;
}

extern "C" void kernel_launch(void* const* d_in, const int* in_sizes, int n_in,
                              void* d_out, int out_size, void* d_ws, size_t ws_size,
                              hipStream_t stream) {
    const float* t  = (const float*)d_in[0];
    const float* W0 = (const float*)d_in[1];
    const float* b0 = (const float*)d_in[2];
    const float* W1 = (const float*)d_in[3];
    const float* b1 = (const float*)d_in[4];
    const float* W2 = (const float*)d_in[5];
    const float* b2 = (const float*)d_in[6];
    const float* W3 = (const float*)d_in[7];
    const float* b3 = (const float*)d_in[8];
    const float* W4 = (const float*)d_in[9];
    const float* b4 = (const float*)d_in[10];
    const float* W5 = (const float*)d_in[11];
    const float* b5 = (const float*)d_in[12];
    const float* W6 = (const float*)d_in[13];
    const float* b6 = (const float*)d_in[14];
    const float* W7 = (const float*)d_in[15];
    const float* b7 = (const float*)d_in[16];
    float* out = (float*)d_out;

    int n = in_sizes[0];             // N points
    int pairs = (n + 1) / 2;         // threads (N=1048576 -> 524288)
    int block = 256;
    int grid = (pairs + block - 1) / block;
    SpringEquationNN_70102456205450_kernel<<<grid, block, 0, stream>>>(
        t, W0, b0, W1, b1, W2, b2, W3, b3, W4, b4, W5, b5, W6, b6, W7, b7,
        out, n);
}